// Round 5
// baseline (402.773 us; speedup 1.0000x reference)
//
#include <hip/hip_runtime.h>
#include <hip/hip_bf16.h>
#include <stdint.h>

#define NRES 384
#define CPAIR 128
#define NHEAD 4
#define DHEAD 32
#define MROWS (NRES * NRES) /* 147456 */
#define QK_SCALE 0.17677669529663687f

typedef unsigned short u16;
typedef short bf16x8 __attribute__((ext_vector_type(8)));
typedef float f32x4 __attribute__((ext_vector_type(4)));

__device__ __forceinline__ u16 f2bf(float f) {
  union { float f; uint32_t u; } c; c.f = f;
  uint32_t u = c.u + 0x7fff + ((c.u >> 16) & 1);   // RNE
  return (u16)(u >> 16);
}
__device__ __forceinline__ float bf2f(u16 h) {
  union { uint32_t u; float f; } c; c.u = ((uint32_t)h) << 16; return c.f;
}
__device__ __forceinline__ u16 f2bf_fast(float f) {  // round-half-up, 2 insts
  union { float f; uint32_t u; } c; c.f = f;
  return (u16)((c.u + 0x8000u) >> 16);
}

// ---------------------------------------------------------------- prep weights
// WcatT[n][k] = Wcat[k][n], n in [0,576): wq|wk|wv|wg|w_bias|zero-pad. woT too.
__global__ void prep_kernel(const float* __restrict__ wq, const float* __restrict__ wk,
                            const float* __restrict__ wv, const float* __restrict__ wg,
                            const float* __restrict__ wb, const float* __restrict__ wo,
                            u16* __restrict__ wcat, u16* __restrict__ wot) {
  int tid = blockIdx.x * blockDim.x + threadIdx.x;
  int stride = gridDim.x * blockDim.x;
  for (int i = tid; i < 576 * 128; i += stride) {
    int n = i >> 7, kk = i & 127;
    float val;
    if (n < 128)      val = wq[kk * 128 + n];
    else if (n < 256) val = wk[kk * 128 + (n - 128)];
    else if (n < 384) val = wv[kk * 128 + (n - 256)];
    else if (n < 512) val = wg[kk * 128 + (n - 384)];
    else if (n < 516) val = wb[kk * 4 + (n - 512)];
    else              val = 0.f;
    wcat[i] = f2bf(val);
  }
  for (int i = tid; i < 128 * 128; i += stride) {
    int n = i >> 7, kk = i & 127;
    wot[i] = f2bf(wo[kk * 128 + n]);
  }
}

// ---------------------------------------------------------------- fused LN + projections
// Block = one 128-row m-tile (wcat restage + barriers halved vs 64-row).
// biasL written in attn C-operand lane order.
__global__ __launch_bounds__(256) void proj_kernel(
    const float* __restrict__ pair, const float* __restrict__ lnw,
    const float* __restrict__ lnb, const u16* __restrict__ wcat,
    u16* __restrict__ q, u16* __restrict__ k, u16* __restrict__ v,
    u16* __restrict__ g, float* __restrict__ biasL) {
  __shared__ __align__(16) u16 xs[128 * 136];  // 34816 B
  __shared__ __align__(16) u16 wsm[64 * 136];  // 17408 B
  const int m0 = blockIdx.x * 128;
  const int tid = threadIdx.x;
  // ---- LayerNorm: 2 passes of 64 rows; thread = (row tid>>2, quarter tid&3)
#pragma unroll
  for (int pass = 0; pass < 2; ++pass) {
    const int row = pass * 64 + (tid >> 2), q4 = tid & 3;
    const float* pr = pair + (size_t)(m0 + row) * CPAIR + q4 * 32;
    float4 vals[8];
    float s1 = 0.f, s2 = 0.f;
#pragma unroll
    for (int i = 0; i < 8; ++i) {
      vals[i] = ((const float4*)pr)[i];
      s1 += (vals[i].x + vals[i].y) + (vals[i].z + vals[i].w);
      s2 += vals[i].x * vals[i].x + vals[i].y * vals[i].y +
            vals[i].z * vals[i].z + vals[i].w * vals[i].w;
    }
    s1 += __shfl_xor(s1, 1); s1 += __shfl_xor(s1, 2);
    s2 += __shfl_xor(s2, 1); s2 += __shfl_xor(s2, 2);
    const float mu = s1 * (1.f / 128.f);
    const float rs = rsqrtf(s2 * (1.f / 128.f) - mu * mu + 1e-5f);
    const float* wr = lnw + q4 * 32;
    const float* br = lnb + q4 * 32;
    uint32_t packed[16];
#pragma unroll
    for (int i = 0; i < 8; ++i) {
      float4 w4 = ((const float4*)wr)[i];
      float4 b4 = ((const float4*)br)[i];
      float y0 = (vals[i].x - mu) * rs * w4.x + b4.x;
      float y1 = (vals[i].y - mu) * rs * w4.y + b4.y;
      float y2 = (vals[i].z - mu) * rs * w4.z + b4.z;
      float y3 = (vals[i].w - mu) * rs * w4.w + b4.w;
      packed[i * 2]     = (uint32_t)f2bf(y0) | ((uint32_t)f2bf(y1) << 16);
      packed[i * 2 + 1] = (uint32_t)f2bf(y2) | ((uint32_t)f2bf(y3) << 16);
    }
#pragma unroll
    for (int i = 0; i < 4; ++i)
      *(uint4*)&xs[row * 136 + q4 * 32 + i * 8] = *(uint4*)&packed[i * 4];
  }
  const int w = tid >> 6, lane = tid & 63, lm = lane & 15, quad = lane >> 4;
  for (int nc = 0; nc < 9; ++nc) {
    __syncthreads();  // prior chunk done with wsm
#pragma unroll
    for (int i = 0; i < 4; ++i) {
      int c = tid + i * 256;
      int row = c >> 4, col8 = (c & 15) * 8;
      *(uint4*)&wsm[row * 136 + col8] =
          *(const uint4*)&wcat[(size_t)(nc * 64 + row) * CPAIR + col8];
    }
    __syncthreads();  // wsm (and first-iter xs) visible
#pragma unroll
    for (int half = 0; half < 2; ++half) {
      f32x4 acc[4] = {{0, 0, 0, 0}, {0, 0, 0, 0}, {0, 0, 0, 0}, {0, 0, 0, 0}};
#pragma unroll
      for (int ks = 0; ks < 4; ++ks) {
        bf16x8 a = *(const bf16x8*)&xs[(half * 64 + w * 16 + lm) * 136 + ks * 32 + quad * 8];
#pragma unroll
        for (int nt = 0; nt < 4; ++nt) {
          bf16x8 bb = *(const bf16x8*)&wsm[(nt * 16 + lm) * 136 + ks * 32 + quad * 8];
          acc[nt] = __builtin_amdgcn_mfma_f32_16x16x32_bf16(a, bb, acc[nt], 0, 0, 0);
        }
      }
#pragma unroll
      for (int nt = 0; nt < 4; ++nt) {
        int n = nc * 64 + nt * 16 + lm;
#pragma unroll
        for (int r = 0; r < 4; ++r) {
          size_t m = (size_t)(m0 + half * 64 + w * 16 + quad * 4 + r);
          float val = acc[nt][r];
          if (n < 128)      q[m * CPAIR + n] = f2bf(val * QK_SCALE);
          else if (n < 256) k[m * CPAIR + (n - 128)] = f2bf(val);
          else if (n < 384) v[m * CPAIR + (n - 256)] = f2bf(val);
          else if (n < 512) g[m * CPAIR + (n - 384)] = f2bf(1.f / (1.f + __expf(-val)));
          else if (n < 516) {
            int h = n - 512;
            int q_idx = (int)(m / NRES), k_idx = (int)(m % NRES);
            int qt = q_idx >> 6, l6 = q_idx & 63;
            int ww = l6 >> 4, qq = (l6 >> 2) & 3, rr = l6 & 3;
            int t = k_idx >> 4, lmm = k_idx & 15;
            size_t idx = ((size_t)((h * 6 + qt) * 24 + t) * 256 +
                          (ww * 64 + qq * 16 + lmm)) * 4 + rr;
            biasL[idx] = val;
          }
        }
      }
    }
  }
}

// ---------------------------------------------------------------- attention
// block=(b,h); 52736 B LDS -> 3 blocks/CU; 2 q-tiles per wave (2 independent
// QK->exp->PV chains) -> 6 chains/SIMD. V B-fragments gathered from global
// once per block into 48 VGPRs (no Vt LDS, no transpose-scatter conflicts).
// Bias enters as MFMA C-operand; no max-subtract (|logits|<~2); P stored
// unnormalized, normalized in epilogue.
__global__ __launch_bounds__(256, 3) void attn_kernel(
    const u16* __restrict__ q, const u16* __restrict__ k, const u16* __restrict__ v,
    const u16* __restrict__ g, const float* __restrict__ biasL, const int* __restrict__ mask,
    u16* __restrict__ og) {
  __shared__ __align__(16) u16 Ks[NRES * 40];    // [kk][dh] stride 40  (30720 B)
  __shared__ __align__(16) u16 Ps[2][128 * 40];  // rows 0-63 qtA, 64-127 qtB (20480 B)
  __shared__ float msk[NRES];                    // 1/0 keep/masked     (1536 B)

  const int b = blockIdx.x, h = blockIdx.y;
  const int tid = threadIdx.x;
  const int w = tid >> 6, lane = tid & 63, lm = lane & 15, quad = lane >> 4;

  const u16* kb = k + (size_t)(b * NRES) * CPAIR + h * DHEAD;
  for (int i = tid; i < NRES * 4; i += 256) {
    int kk = i >> 2, c8 = (i & 3) * 8;
    *(uint4*)&Ks[kk * 40 + c8] = *(const uint4*)&kb[(size_t)kk * CPAIR + c8];
  }
  for (int i = tid; i < NRES; i += 256)
    msk[i] = (mask[b * NRES + i] > 0) ? 1.f : 0.f;

  // V B-fragments from global: vf[c][j] = V[kk = c*32+quad*8+j][dh = lm (+16)]
  const u16* vb = v + (size_t)(b * NRES) * CPAIR + h * DHEAD;
  bf16x8 vf0[12], vf1[12];
#pragma unroll
  for (int c = 0; c < 12; ++c) {
#pragma unroll
    for (int j = 0; j < 8; ++j) {
      size_t roff = (size_t)(c * 32 + quad * 8 + j) * CPAIR;
      vf0[c][j] = (short)vb[roff + lm];
      vf1[c][j] = (short)vb[roff + 16 + lm];
    }
  }
  __syncthreads();

  for (int it = 0; it < 3; ++it) {
    const int qA = it * 64, qB = (it + 3) * 64;
    bf16x8 afA = *(const bf16x8*)&q[(size_t)(b * NRES + qA + w * 16 + lm) * CPAIR +
                                    h * DHEAD + quad * 8];
    bf16x8 afB = *(const bf16x8*)&q[(size_t)(b * NRES + qB + w * 16 + lm) * CPAIR +
                                    h * DHEAD + quad * 8];
    const float* bpA = biasL + ((size_t)(h * 6 + it) * 24) * 1024 + tid * 4;
    const float* bpB = biasL + ((size_t)(h * 6 + it + 3) * 24) * 1024 + tid * 4;
    f32x4 rsA = {0, 0, 0, 0}, rsB = {0, 0, 0, 0};
    f32x4 oA0 = {0, 0, 0, 0}, oA1 = {0, 0, 0, 0};
    f32x4 oB0 = {0, 0, 0, 0}, oB1 = {0, 0, 0, 0};
#pragma unroll
    for (int c = 0; c < 12; ++c) {
      f32x4 sA[2], sB[2];
#pragma unroll
      for (int tl = 0; tl < 2; ++tl) {
        int t = c * 2 + tl;
        bf16x8 kf = *(const bf16x8*)&Ks[(t * 16 + lm) * 40 + quad * 8];
        sA[tl] = __builtin_amdgcn_mfma_f32_16x16x32_bf16(
            afA, kf, *(const f32x4*)(bpA + t * 1024), 0, 0, 0);
        sB[tl] = __builtin_amdgcn_mfma_f32_16x16x32_bf16(
            afB, kf, *(const f32x4*)(bpB + t * 1024), 0, 0, 0);
      }
      u16* PsC = Ps[c & 1];
#pragma unroll
      for (int tl = 0; tl < 2; ++tl) {
        float m = msk[(c * 2 + tl) * 16 + lm];
#pragma unroll
        for (int r = 0; r < 4; ++r) {
          float pA = __expf(sA[tl][r]) * m;   // unnormalized
          float pB = __expf(sB[tl][r]) * m;
          rsA[r] += pA;
          rsB[r] += pB;
          PsC[(w * 16 + quad * 4 + r) * 40 + tl * 16 + lm] = f2bf_fast(pA);
          PsC[(64 * 40) + (w * 16 + quad * 4 + r) * 40 + tl * 16 + lm] = f2bf_fast(pB);
        }
      }
      // per-wave LDS ops are in-order: reads below see this wave's writes above
      bf16x8 paA = *(const bf16x8*)&PsC[(w * 16 + lm) * 40 + quad * 8];
      bf16x8 paB = *(const bf16x8*)&PsC[(64 * 40) + (w * 16 + lm) * 40 + quad * 8];
      oA0 = __builtin_amdgcn_mfma_f32_16x16x32_bf16(paA, vf0[c], oA0, 0, 0, 0);
      oA1 = __builtin_amdgcn_mfma_f32_16x16x32_bf16(paA, vf1[c], oA1, 0, 0, 0);
      oB0 = __builtin_amdgcn_mfma_f32_16x16x32_bf16(paB, vf0[c], oB0, 0, 0, 0);
      oB1 = __builtin_amdgcn_mfma_f32_16x16x32_bf16(paB, vf1[c], oB1, 0, 0, 0);
    }
#pragma unroll
    for (int r = 0; r < 4; ++r) {
      rsA[r] += __shfl_xor(rsA[r], 8);
      rsA[r] += __shfl_xor(rsA[r], 4);
      rsA[r] += __shfl_xor(rsA[r], 2);
      rsA[r] += __shfl_xor(rsA[r], 1);
      rsB[r] += __shfl_xor(rsB[r], 8);
      rsB[r] += __shfl_xor(rsB[r], 4);
      rsB[r] += __shfl_xor(rsB[r], 2);
      rsB[r] += __shfl_xor(rsB[r], 1);
    }
#pragma unroll
    for (int r = 0; r < 4; ++r) {
      float riA = 1.f / rsA[r], riB = 1.f / rsB[r];
      size_t mA = (size_t)(b * NRES + qA + w * 16 + quad * 4 + r);
      size_t mB = (size_t)(b * NRES + qB + w * 16 + quad * 4 + r);
      int c0 = h * DHEAD + lm, c1 = c0 + 16;
      og[mA * CPAIR + c0] = f2bf(oA0[r] * riA * bf2f(g[mA * CPAIR + c0]));
      og[mA * CPAIR + c1] = f2bf(oA1[r] * riA * bf2f(g[mA * CPAIR + c1]));
      og[mB * CPAIR + c0] = f2bf(oB0[r] * riB * bf2f(g[mB * CPAIR + c0]));
      og[mB * CPAIR + c1] = f2bf(oB1[r] * riB * bf2f(g[mB * CPAIR + c1]));
    }
  }
}

// ---------------------------------------------------------------- out = og @ wo
// Block = one 128-row m-tile; og staged once, 2 n-chunks of wot looped.
__global__ __launch_bounds__(256) void outproj_kernel(const u16* __restrict__ og,
                                                      const u16* __restrict__ wot,
                                                      float* __restrict__ out) {
  __shared__ __align__(16) u16 xs[128 * 136];
  __shared__ __align__(16) u16 wsm[64 * 136];
  const int m0 = blockIdx.x * 128;
  const int tid = threadIdx.x;
#pragma unroll
  for (int i = 0; i < 8; ++i) {
    int c = tid + i * 256;
    int row = c >> 4, col8 = (c & 15) * 8;
    *(uint4*)&xs[row * 136 + col8] = *(const uint4*)&og[(size_t)(m0 + row) * CPAIR + col8];
  }
  const int w = tid >> 6, lane = tid & 63, lm = lane & 15, quad = lane >> 4;
  for (int nc = 0; nc < 2; ++nc) {
    __syncthreads();
#pragma unroll
    for (int i = 0; i < 4; ++i) {
      int c = tid + i * 256;
      int row = c >> 4, col8 = (c & 15) * 8;
      *(uint4*)&wsm[row * 136 + col8] =
          *(const uint4*)&wot[(size_t)(nc * 64 + row) * CPAIR + col8];
    }
    __syncthreads();
#pragma unroll
    for (int half = 0; half < 2; ++half) {
      f32x4 acc[4] = {{0, 0, 0, 0}, {0, 0, 0, 0}, {0, 0, 0, 0}, {0, 0, 0, 0}};
#pragma unroll
      for (int ks = 0; ks < 4; ++ks) {
        bf16x8 a = *(const bf16x8*)&xs[(half * 64 + w * 16 + lm) * 136 + ks * 32 + quad * 8];
#pragma unroll
        for (int nt = 0; nt < 4; ++nt) {
          bf16x8 bb = *(const bf16x8*)&wsm[(nt * 16 + lm) * 136 + ks * 32 + quad * 8];
          acc[nt] = __builtin_amdgcn_mfma_f32_16x16x32_bf16(a, bb, acc[nt], 0, 0, 0);
        }
      }
#pragma unroll
      for (int nt = 0; nt < 4; ++nt) {
        int n = nc * 64 + nt * 16 + lm;
#pragma unroll
        for (int r = 0; r < 4; ++r) {
          size_t m = (size_t)(m0 + half * 64 + w * 16 + quad * 4 + r);
          out[m * CPAIR + n] = acc[nt][r];
        }
      }
    }
  }
}

// ---------------------------------------------------------------- launch
extern "C" void kernel_launch(void* const* d_in, const int* in_sizes, int n_in,
                              void* d_out, int out_size, void* d_ws, size_t ws_size,
                              hipStream_t stream) {
  const float* pair = (const float*)d_in[0];
  const int* mask = (const int*)d_in[1];
  const float* ln_w = (const float*)d_in[2];
  const float* ln_b = (const float*)d_in[3];
  const float* w_bias = (const float*)d_in[4];
  const float* wq = (const float*)d_in[5];
  const float* wk = (const float*)d_in[6];
  const float* wv = (const float*)d_in[7];
  const float* wg = (const float*)d_in[8];
  const float* wo = (const float*)d_in[9];
  float* out = (float*)d_out;

  // d_out doubles as scratch for q + gate; both dead before outproj writes out.
  u16* qb = (u16*)d_out;
  u16* gb = qb + (size_t)MROWS * CPAIR;

  char* ws = (char*)d_ws;
  const size_t SZ = (size_t)MROWS * CPAIR * 2;  // one bf16 [M][128] buffer
  u16* og = (u16*)(ws);
  u16* kb = (u16*)(ws + SZ);
  u16* vb = (u16*)(ws + 2 * SZ);
  float* biasL = (float*)(ws + 3 * SZ);                       // [H][M] f32, lane order
  u16* wcat = (u16*)(ws + 3 * SZ + (size_t)NHEAD * MROWS * 4);
  u16* wot = wcat + 576 * 128;

  hipLaunchKernelGGL(prep_kernel, dim3(64), dim3(256), 0, stream,
                     wq, wk, wv, wg, w_bias, wo, wcat, wot);
  hipLaunchKernelGGL(proj_kernel, dim3(MROWS / 128), dim3(256), 0, stream,
                     pair, ln_w, ln_b, wcat, qb, kb, vb, gb, biasL);
  hipLaunchKernelGGL(attn_kernel, dim3(NRES, NHEAD), dim3(256), 0, stream,
                     qb, kb, vb, gb, biasL, mask, og);
  hipLaunchKernelGGL(outproj_kernel, dim3(MROWS / 128), dim3(256), 0, stream,
                     og, wot, out);
}